// Round 3
// baseline (1409.552 us; speedup 1.0000x reference)
//
#include <hip/hip_runtime.h>
#include <math.h>

#define DIM   1024
#define NH    16
#define HD    64
#define BATCH 2
#define SEQ   2048
#define EPS   1e-6f

// Dtype-adaptive build: a detect kernel decides at runtime whether the float
// inputs arrived as fp32 (reference says jnp.float32) or were converted to
// bf16 by the harness. flag=1 -> fp32, flag=0 -> bf16. All branches on the
// flag are block-uniform. Internal workspace is always fp32.

__device__ __forceinline__ float bf2f(unsigned short u) {
  return __uint_as_float(((unsigned int)u) << 16);
}
__device__ __forceinline__ unsigned short f2bf(float f) {
  unsigned int u = __float_as_uint(f);
  unsigned int r = (u + 0x7FFFu + ((u >> 16) & 1u)) >> 16;  // RNE
  return (unsigned short)r;
}

// ---------------------------------------------------------------------------
// Dtype detector: scan first 4096 uint16 of w_qkv. True-bf16 weights have
// |w| <= 0.045 -> bf16 exponent field < 127 always. fp32-misread lower halves
// are uniform -> ~half have exponent field >= 127.
// ---------------------------------------------------------------------------
__global__ void detect_dtype(const unsigned short* __restrict__ w, int* __restrict__ flag) {
  __shared__ int cnt;
  if (threadIdx.x == 0) cnt = 0;
  __syncthreads();
  int c = 0;
  for (int i = threadIdx.x; i < 4096; i += 256) {
    unsigned short u = w[i];
    if ((u & 0x7F80u) >= 0x3F80u) ++c;  // |value as bf16| >= 1.0
  }
  atomicAdd(&cnt, c);
  __syncthreads();
  if (threadIdx.x == 0) *flag = (cnt >= 64) ? 1 : 0;  // 1 = fp32 inputs
}

// ---------------------------------------------------------------------------
// GEMM: C[M,N] = A[M,K] * B[N,K]^T (+bias over N). Row-major, contiguous K.
// 128x128 tile, BK=16, 256 threads, 8x8/thread (4+4 split micro-tile).
// A_IS_WS: A is fp32 workspace (ignore flag). Else A is an input (flag dtype).
// B is always an input (flag dtype).
// QKV_STORE: scatter fp32 into q/k/v planes [B*H][S][HD]; else store to
// output in flag dtype, adding bias (flag dtype).
// ---------------------------------------------------------------------------
#define TS 128
#define KT 16

template <bool A_IS_WS, bool QKV_STORE>
__global__ __launch_bounds__(256)
void gemm_nt(const void* __restrict__ Av, const void* __restrict__ Bv,
             const void* __restrict__ biasv, void* __restrict__ Cv,
             int M, int N, int K, const int* __restrict__ flagp) {
  __shared__ float As[KT][TS + 4];
  __shared__ float Bs[KT][TS + 4];

  const bool isf32 = (*flagp != 0);
  const int tid = threadIdx.x;
  const int tx = tid & 15;   // N direction
  const int ty = tid >> 4;   // M direction
  const int bm = blockIdx.y * TS;
  const int bn = blockIdx.x * TS;

  float acc[8][8];
#pragma unroll
  for (int i = 0; i < 8; ++i)
#pragma unroll
    for (int j = 0; j < 8; ++j) acc[i][j] = 0.f;

  for (int k0 = 0; k0 < K; k0 += KT) {
    // ---- stage A tile ----
    if (A_IS_WS || isf32) {
      const float* A = (const float*)Av;
#pragma unroll
      for (int L = tid; L < 512; L += 256) {
        const int row = L >> 2;
        const int kc  = (L & 3) << 2;
        float4 av = *(const float4*)&A[(size_t)(bm + row) * K + k0 + kc];
        As[kc + 0][row] = av.x; As[kc + 1][row] = av.y;
        As[kc + 2][row] = av.z; As[kc + 3][row] = av.w;
      }
    } else {
      const unsigned short* A = (const unsigned short*)Av;
      const int row = tid >> 1;
      const int kh = (tid & 1) * 8;
      uint4 w = *(const uint4*)&A[(size_t)(bm + row) * K + k0 + kh];
      As[kh + 0][row] = bf2f((unsigned short)(w.x & 0xFFFF));
      As[kh + 1][row] = bf2f((unsigned short)(w.x >> 16));
      As[kh + 2][row] = bf2f((unsigned short)(w.y & 0xFFFF));
      As[kh + 3][row] = bf2f((unsigned short)(w.y >> 16));
      As[kh + 4][row] = bf2f((unsigned short)(w.z & 0xFFFF));
      As[kh + 5][row] = bf2f((unsigned short)(w.z >> 16));
      As[kh + 6][row] = bf2f((unsigned short)(w.w & 0xFFFF));
      As[kh + 7][row] = bf2f((unsigned short)(w.w >> 16));
    }
    // ---- stage B tile ----
    if (isf32) {
      const float* B = (const float*)Bv;
#pragma unroll
      for (int L = tid; L < 512; L += 256) {
        const int row = L >> 2;
        const int kc  = (L & 3) << 2;
        float4 bv = *(const float4*)&B[(size_t)(bn + row) * K + k0 + kc];
        Bs[kc + 0][row] = bv.x; Bs[kc + 1][row] = bv.y;
        Bs[kc + 2][row] = bv.z; Bs[kc + 3][row] = bv.w;
      }
    } else {
      const unsigned short* B = (const unsigned short*)Bv;
      const int row = tid >> 1;
      const int kh = (tid & 1) * 8;
      uint4 w = *(const uint4*)&B[(size_t)(bn + row) * K + k0 + kh];
      Bs[kh + 0][row] = bf2f((unsigned short)(w.x & 0xFFFF));
      Bs[kh + 1][row] = bf2f((unsigned short)(w.x >> 16));
      Bs[kh + 2][row] = bf2f((unsigned short)(w.y & 0xFFFF));
      Bs[kh + 3][row] = bf2f((unsigned short)(w.y >> 16));
      Bs[kh + 4][row] = bf2f((unsigned short)(w.z & 0xFFFF));
      Bs[kh + 5][row] = bf2f((unsigned short)(w.z >> 16));
      Bs[kh + 6][row] = bf2f((unsigned short)(w.w & 0xFFFF));
      Bs[kh + 7][row] = bf2f((unsigned short)(w.w >> 16));
    }
    __syncthreads();

#pragma unroll
    for (int kk = 0; kk < KT; ++kk) {
      float a[8], b[8];
      *(float4*)&a[0] = *(const float4*)&As[kk][ty * 4];
      *(float4*)&a[4] = *(const float4*)&As[kk][64 + ty * 4];
      *(float4*)&b[0] = *(const float4*)&Bs[kk][tx * 4];
      *(float4*)&b[4] = *(const float4*)&Bs[kk][64 + tx * 4];
#pragma unroll
      for (int i = 0; i < 8; ++i)
#pragma unroll
        for (int j = 0; j < 8; ++j) acc[i][j] = fmaf(a[i], b[j], acc[i][j]);
    }
    __syncthreads();
  }

  // epilogue
#pragma unroll
  for (int i = 0; i < 8; ++i) {
    const int r = bm + ((i < 4) ? (ty * 4 + i) : (64 + ty * 4 + (i - 4)));
#pragma unroll
    for (int half = 0; half < 2; ++half) {
      const int n0 = bn + half * 64 + tx * 4;
      float4 v;
      v.x = acc[i][half * 4 + 0];
      v.y = acc[i][half * 4 + 1];
      v.z = acc[i][half * 4 + 2];
      v.w = acc[i][half * 4 + 3];
      if (QKV_STORE) {
        float* C = (float*)Cv;
        const int b = r >> 11, s = r & 2047;
        const int j = n0 >> 10, h = (n0 >> 6) & 15, d0 = n0 & 63;
        const size_t dst = (size_t)j * (BATCH * NH * SEQ * HD) +
                           (((size_t)((b << 4) + h)) * SEQ + s) * HD + d0;
        *(float4*)&C[dst] = v;
      } else {
        if (isf32) {
          const float* bias = (const float*)biasv;
          float4 bb = *(const float4*)&bias[n0];
          v.x += bb.x; v.y += bb.y; v.z += bb.z; v.w += bb.w;
          float* C = (float*)Cv;
          *(float4*)&C[(size_t)r * N + n0] = v;
        } else {
          const unsigned short* bias = (const unsigned short*)biasv;
          ushort4 bb = *(const ushort4*)&bias[n0];
          v.x += bf2f(bb.x); v.y += bf2f(bb.y);
          v.z += bf2f(bb.z); v.w += bf2f(bb.w);
          unsigned short* C = (unsigned short*)Cv;
          ushort4 st;
          st.x = f2bf(v.x); st.y = f2bf(v.y);
          st.z = f2bf(v.z); st.w = f2bf(v.w);
          *(ushort4*)&C[(size_t)r * N + n0] = st;
        }
      }
    }
  }
}

// ---------------------------------------------------------------------------
// Per-head LayerNorm + RoPE in place on fp32 q/k planes [B*H][S][HD].
// One wave per (b,s,h): lane = head dim. rotate_half partner = lane^32.
// NOTE: sincosf is (x, &sin, &cos) — sin FIRST. (Round-1/2 bug was the swap.)
// ---------------------------------------------------------------------------
__device__ __forceinline__ float wave_sum64(float v) {
#pragma unroll
  for (int o = 32; o; o >>= 1) v += __shfl_xor(v, o);
  return v;
}

__global__ __launch_bounds__(256)
void ln_rope(float* __restrict__ Qb, float* __restrict__ Kb,
             const void* __restrict__ qgv, const void* __restrict__ qbv,
             const void* __restrict__ kgv, const void* __restrict__ kbv,
             const int* __restrict__ flagp) {
  const bool isf32 = (*flagp != 0);
  const int tid = threadIdx.x;
  const int w = blockIdx.x * 4 + (tid >> 6);  // index over B*H*S
  const int d = tid & 63;
  const int s = w & (SEQ - 1);
  const size_t idx = (size_t)w * HD + d;

  float qg, qb, kg, kb;
  if (isf32) {
    qg = ((const float*)qgv)[d]; qb = ((const float*)qbv)[d];
    kg = ((const float*)kgv)[d]; kb = ((const float*)kbv)[d];
  } else {
    qg = bf2f(((const unsigned short*)qgv)[d]); qb = bf2f(((const unsigned short*)qbv)[d]);
    kg = bf2f(((const unsigned short*)kgv)[d]); kb = bf2f(((const unsigned short*)kbv)[d]);
  }

  float qv = Qb[idx], kv = Kb[idx];

  float mu = wave_sum64(qv) * (1.f / 64.f);
  float dq = qv - mu;
  float var = wave_sum64(dq * dq) * (1.f / 64.f);
  float qn = dq * rsqrtf(var + EPS) * qg + qb;

  mu = wave_sum64(kv) * (1.f / 64.f);
  float dk = kv - mu;
  var = wave_sum64(dk * dk) * (1.f / 64.f);
  float kn = dk * rsqrtf(var + EPS) * kg + kb;

  // RoPE: inv_freq = 10000^{-(d&31)/32}
  const float fr = (float)(d & 31) * (1.f / 32.f);
  const float inv_freq = expf(-fr * 9.210340371976184f);
  const float ang = (float)s * inv_freq;
  float sn, cs;
  sincosf(ang, &sn, &cs);  // sin first!
  const float sgn = (d < 32) ? -1.f : 1.f;
  const float qp = __shfl_xor(qn, 32);
  const float kp = __shfl_xor(kn, 32);
  const float qr = qn * cs + sgn * qp * sn;
  const float kr = kn * cs + sgn * kp * sn;

  Qb[idx] = qr * 0.125f;  // fold in D^-0.5
  Kb[idx] = kr;
}

// ---------------------------------------------------------------------------
// Flash attention (fp32): grid (S/64, B*H), 256 threads.
// Thread (r=tid>>2, c=tid&3): query row r; c splits keys (kk=c+4j) and out
// dims (c*16..). Online softmax state consistent across c-lanes via shuffles.
// ---------------------------------------------------------------------------
__global__ __launch_bounds__(256)
void attn(const float* __restrict__ Q, const float* __restrict__ Kg,
          const float* __restrict__ Vg, float* __restrict__ O) {
  __shared__ float Ks[64][68];
  __shared__ float Vs[64][68];
  __shared__ float Ps[64][65];

  const int tid = threadIdx.x;
  const int r = tid >> 2;
  const int c = tid & 3;
  const int bh = blockIdx.y;
  const int q0 = blockIdx.x * 64;
  const size_t base = (size_t)bh * (SEQ * HD);

  float4 qv[16];
  const float4* qrow = (const float4*)(Q + base + (size_t)(q0 + r) * HD);
#pragma unroll
  for (int i = 0; i < 16; ++i) qv[i] = qrow[i];

  float m_run = -1e30f, l_run = 0.f;
  float oacc[16];
#pragma unroll
  for (int i = 0; i < 16; ++i) oacc[i] = 0.f;

  for (int kt = 0; kt < SEQ; kt += 64) {
    __syncthreads();
    {
      const float4* krow = (const float4*)(Kg + base + (size_t)(kt + r) * HD + c * 16);
      const float4* vrow = (const float4*)(Vg + base + (size_t)(kt + r) * HD + c * 16);
#pragma unroll
      for (int i = 0; i < 4; ++i) {
        *(float4*)&Ks[r][c * 16 + i * 4] = krow[i];
        *(float4*)&Vs[r][c * 16 + i * 4] = vrow[i];
      }
    }
    __syncthreads();

    float sc[16];
    float tmax = -1e30f;
#pragma unroll
    for (int j = 0; j < 16; ++j) {
      const int kk = c + (j << 2);
      const float4* kr4 = (const float4*)&Ks[kk][0];
      float dot = 0.f;
#pragma unroll
      for (int i = 0; i < 16; ++i) {
        float4 k4 = kr4[i];
        dot = fmaf(qv[i].x, k4.x, dot);
        dot = fmaf(qv[i].y, k4.y, dot);
        dot = fmaf(qv[i].z, k4.z, dot);
        dot = fmaf(qv[i].w, k4.w, dot);
      }
      sc[j] = dot;
      tmax = fmaxf(tmax, dot);
    }
    tmax = fmaxf(tmax, __shfl_xor(tmax, 1));
    tmax = fmaxf(tmax, __shfl_xor(tmax, 2));

    const float m_new = fmaxf(m_run, tmax);
    const float alpha = __expf(m_run - m_new);
    float psum = 0.f;
#pragma unroll
    for (int j = 0; j < 16; ++j) {
      const float p = __expf(sc[j] - m_new);
      Ps[r][c + (j << 2)] = p;
      psum += p;
    }
    psum += __shfl_xor(psum, 1);
    psum += __shfl_xor(psum, 2);
    l_run = l_run * alpha + psum;
    m_run = m_new;
#pragma unroll
    for (int i = 0; i < 16; ++i) oacc[i] *= alpha;
    __syncthreads();

#pragma unroll 8
    for (int kk = 0; kk < 64; ++kk) {
      const float p = Ps[r][kk];
      const float4* vr4 = (const float4*)&Vs[kk][c * 16];
#pragma unroll
      for (int i = 0; i < 4; ++i) {
        float4 v4 = vr4[i];
        oacc[i * 4 + 0] = fmaf(p, v4.x, oacc[i * 4 + 0]);
        oacc[i * 4 + 1] = fmaf(p, v4.y, oacc[i * 4 + 1]);
        oacc[i * 4 + 2] = fmaf(p, v4.z, oacc[i * 4 + 2]);
        oacc[i * 4 + 3] = fmaf(p, v4.w, oacc[i * 4 + 3]);
      }
    }
  }

  const float inv_l = 1.f / l_run;
  const int b = bh >> 4, h = bh & 15;
  float* orow = O + ((size_t)(b * SEQ + q0 + r)) * DIM + h * HD + c * 16;
#pragma unroll
  for (int i = 0; i < 4; ++i) {
    float4 o4;
    o4.x = oacc[i * 4 + 0] * inv_l;
    o4.y = oacc[i * 4 + 1] * inv_l;
    o4.z = oacc[i * 4 + 2] * inv_l;
    o4.w = oacc[i * 4 + 3] * inv_l;
    *(float4*)&orow[i * 4] = o4;
  }
}

// ---------------------------------------------------------------------------
extern "C" void kernel_launch(void* const* d_in, const int* in_sizes, int n_in,
                              void* d_out, int out_size, void* d_ws, size_t ws_size,
                              hipStream_t stream) {
  const void* x      = d_in[0];
  const void* w_qkv  = d_in[1];
  const void* w_proj = d_in[2];
  const void* b_proj = d_in[3];
  const void* q_g    = d_in[4];
  const void* q_b    = d_in[5];
  const void* k_g    = d_in[6];
  const void* k_b    = d_in[7];

  const size_t PLANE = (size_t)BATCH * NH * SEQ * HD;  // 4 Mi elements
  float* qbuf = (float*)d_ws;
  float* kbuf = qbuf + PLANE;
  float* vbuf = qbuf + 2 * PLANE;
  float* attnout = qbuf + 3 * PLANE;
  int* flag = (int*)(qbuf + 4 * PLANE);  // needs ws >= 64 MiB + 4 B

  // 0) dtype detection (fp32 vs bf16 inputs)
  hipLaunchKernelGGL(detect_dtype, dim3(1), dim3(256), 0, stream,
                     (const unsigned short*)w_qkv, flag);

  // 1) QKV projection, permuted fp32 store [3][B*H][S][HD]
  {
    dim3 grid((3 * DIM) / TS, (BATCH * SEQ) / TS);
    hipLaunchKernelGGL((gemm_nt<false, true>), grid, dim3(256), 0, stream,
                       x, w_qkv, (const void*)nullptr, (void*)qbuf,
                       BATCH * SEQ, 3 * DIM, DIM, flag);
  }
  // 2) LayerNorm + RoPE in place on q,k
  {
    dim3 grid((BATCH * NH * SEQ) / 4);
    hipLaunchKernelGGL(ln_rope, grid, dim3(256), 0, stream,
                       qbuf, kbuf, q_g, q_b, k_g, k_b, flag);
  }
  // 3) flash attention -> attnout [B][S][DIM] fp32
  {
    dim3 grid(SEQ / 64, BATCH * NH);
    hipLaunchKernelGGL(attn, grid, dim3(256), 0, stream,
                       qbuf, kbuf, vbuf, attnout);
  }
  // 4) output projection + bias -> d_out (flag dtype)
  {
    dim3 grid(DIM / TS, (BATCH * SEQ) / TS);
    hipLaunchKernelGGL((gemm_nt<true, false>), grid, dim3(256), 0, stream,
                       (const void*)attnout, w_proj, b_proj, d_out,
                       BATCH * SEQ, DIM, DIM, flag);
  }
}

// Round 4
// 747.165 us; speedup vs baseline: 1.8865x; 1.8865x over previous
//
#include <hip/hip_runtime.h>
#include <math.h>

#define DIM   1024
#define NH    16
#define HD    64
#define BATCH 2
#define SEQ   2048
#define EPS   1e-6f

typedef __attribute__((ext_vector_type(8))) short bf16x8;
typedef __attribute__((ext_vector_type(4))) float f32x4;

__device__ __forceinline__ float bf2f(unsigned short u) {
  return __uint_as_float(((unsigned int)u) << 16);
}
__device__ __forceinline__ unsigned short f2bf(float f) {
  unsigned int u = __float_as_uint(f);
  unsigned int r = (u + 0x7FFFu + ((u >> 16) & 1u)) >> 16;  // RNE
  return (unsigned short)r;
}

// ---------------------------------------------------------------------------
// Dtype detector (unchanged from round 3, which passed): flag=1 -> fp32 in.
// ---------------------------------------------------------------------------
__global__ void detect_dtype(const unsigned short* __restrict__ w, int* __restrict__ flag) {
  __shared__ int cnt;
  if (threadIdx.x == 0) cnt = 0;
  __syncthreads();
  int c = 0;
  for (int i = threadIdx.x; i < 4096; i += 256) {
    unsigned short u = w[i];
    if ((u & 0x7F80u) >= 0x3F80u) ++c;
  }
  atomicAdd(&cnt, c);
  __syncthreads();
  if (threadIdx.x == 0) *flag = (cnt >= 64) ? 1 : 0;
}

// ---------------------------------------------------------------------------
// GEMM (unchanged from round 3): C[M,N] = A[M,K] * B[N,K]^T (+bias).
// ---------------------------------------------------------------------------
#define TS 128
#define KT 16

template <bool A_IS_WS, bool QKV_STORE>
__global__ __launch_bounds__(256)
void gemm_nt(const void* __restrict__ Av, const void* __restrict__ Bv,
             const void* __restrict__ biasv, void* __restrict__ Cv,
             int M, int N, int K, const int* __restrict__ flagp) {
  __shared__ float As[KT][TS + 4];
  __shared__ float Bs[KT][TS + 4];

  const bool isf32 = (*flagp != 0);
  const int tid = threadIdx.x;
  const int tx = tid & 15;
  const int ty = tid >> 4;
  const int bm = blockIdx.y * TS;
  const int bn = blockIdx.x * TS;

  float acc[8][8];
#pragma unroll
  for (int i = 0; i < 8; ++i)
#pragma unroll
    for (int j = 0; j < 8; ++j) acc[i][j] = 0.f;

  for (int k0 = 0; k0 < K; k0 += KT) {
    if (A_IS_WS || isf32) {
      const float* A = (const float*)Av;
#pragma unroll
      for (int L = tid; L < 512; L += 256) {
        const int row = L >> 2;
        const int kc  = (L & 3) << 2;
        float4 av = *(const float4*)&A[(size_t)(bm + row) * K + k0 + kc];
        As[kc + 0][row] = av.x; As[kc + 1][row] = av.y;
        As[kc + 2][row] = av.z; As[kc + 3][row] = av.w;
      }
    } else {
      const unsigned short* A = (const unsigned short*)Av;
      const int row = tid >> 1;
      const int kh = (tid & 1) * 8;
      uint4 w = *(const uint4*)&A[(size_t)(bm + row) * K + k0 + kh];
      As[kh + 0][row] = bf2f((unsigned short)(w.x & 0xFFFF));
      As[kh + 1][row] = bf2f((unsigned short)(w.x >> 16));
      As[kh + 2][row] = bf2f((unsigned short)(w.y & 0xFFFF));
      As[kh + 3][row] = bf2f((unsigned short)(w.y >> 16));
      As[kh + 4][row] = bf2f((unsigned short)(w.z & 0xFFFF));
      As[kh + 5][row] = bf2f((unsigned short)(w.z >> 16));
      As[kh + 6][row] = bf2f((unsigned short)(w.w & 0xFFFF));
      As[kh + 7][row] = bf2f((unsigned short)(w.w >> 16));
    }
    if (isf32) {
      const float* B = (const float*)Bv;
#pragma unroll
      for (int L = tid; L < 512; L += 256) {
        const int row = L >> 2;
        const int kc  = (L & 3) << 2;
        float4 bv = *(const float4*)&B[(size_t)(bn + row) * K + k0 + kc];
        Bs[kc + 0][row] = bv.x; Bs[kc + 1][row] = bv.y;
        Bs[kc + 2][row] = bv.z; Bs[kc + 3][row] = bv.w;
      }
    } else {
      const unsigned short* B = (const unsigned short*)Bv;
      const int row = tid >> 1;
      const int kh = (tid & 1) * 8;
      uint4 w = *(const uint4*)&B[(size_t)(bn + row) * K + k0 + kh];
      Bs[kh + 0][row] = bf2f((unsigned short)(w.x & 0xFFFF));
      Bs[kh + 1][row] = bf2f((unsigned short)(w.x >> 16));
      Bs[kh + 2][row] = bf2f((unsigned short)(w.y & 0xFFFF));
      Bs[kh + 3][row] = bf2f((unsigned short)(w.y >> 16));
      Bs[kh + 4][row] = bf2f((unsigned short)(w.z & 0xFFFF));
      Bs[kh + 5][row] = bf2f((unsigned short)(w.z >> 16));
      Bs[kh + 6][row] = bf2f((unsigned short)(w.w & 0xFFFF));
      Bs[kh + 7][row] = bf2f((unsigned short)(w.w >> 16));
    }
    __syncthreads();

#pragma unroll
    for (int kk = 0; kk < KT; ++kk) {
      float a[8], b[8];
      *(float4*)&a[0] = *(const float4*)&As[kk][ty * 4];
      *(float4*)&a[4] = *(const float4*)&As[kk][64 + ty * 4];
      *(float4*)&b[0] = *(const float4*)&Bs[kk][tx * 4];
      *(float4*)&b[4] = *(const float4*)&Bs[kk][64 + tx * 4];
#pragma unroll
      for (int i = 0; i < 8; ++i)
#pragma unroll
        for (int j = 0; j < 8; ++j) acc[i][j] = fmaf(a[i], b[j], acc[i][j]);
    }
    __syncthreads();
  }

#pragma unroll
  for (int i = 0; i < 8; ++i) {
    const int r = bm + ((i < 4) ? (ty * 4 + i) : (64 + ty * 4 + (i - 4)));
#pragma unroll
    for (int half = 0; half < 2; ++half) {
      const int n0 = bn + half * 64 + tx * 4;
      float4 v;
      v.x = acc[i][half * 4 + 0];
      v.y = acc[i][half * 4 + 1];
      v.z = acc[i][half * 4 + 2];
      v.w = acc[i][half * 4 + 3];
      if (QKV_STORE) {
        float* C = (float*)Cv;
        const int b = r >> 11, s = r & 2047;
        const int j = n0 >> 10, h = (n0 >> 6) & 15, d0 = n0 & 63;
        const size_t dst = (size_t)j * (BATCH * NH * SEQ * HD) +
                           (((size_t)((b << 4) + h)) * SEQ + s) * HD + d0;
        *(float4*)&C[dst] = v;
      } else {
        if (isf32) {
          const float* bias = (const float*)biasv;
          float4 bb = *(const float4*)&bias[n0];
          v.x += bb.x; v.y += bb.y; v.z += bb.z; v.w += bb.w;
          float* C = (float*)Cv;
          *(float4*)&C[(size_t)r * N + n0] = v;
        } else {
          const unsigned short* bias = (const unsigned short*)biasv;
          ushort4 bb = *(const ushort4*)&bias[n0];
          v.x += bf2f(bb.x); v.y += bf2f(bb.y);
          v.z += bf2f(bb.z); v.w += bf2f(bb.w);
          unsigned short* C = (unsigned short*)Cv;
          ushort4 st;
          st.x = f2bf(v.x); st.y = f2bf(v.y);
          st.z = f2bf(v.z); st.w = f2bf(v.w);
          *(ushort4*)&C[(size_t)r * N + n0] = st;
        }
      }
    }
  }
}

// ---------------------------------------------------------------------------
// LayerNorm + RoPE (unchanged from round 3).
// ---------------------------------------------------------------------------
__device__ __forceinline__ float wave_sum64(float v) {
#pragma unroll
  for (int o = 32; o; o >>= 1) v += __shfl_xor(v, o);
  return v;
}

__global__ __launch_bounds__(256)
void ln_rope(float* __restrict__ Qb, float* __restrict__ Kb,
             const void* __restrict__ qgv, const void* __restrict__ qbv,
             const void* __restrict__ kgv, const void* __restrict__ kbv,
             const int* __restrict__ flagp) {
  const bool isf32 = (*flagp != 0);
  const int tid = threadIdx.x;
  const int w = blockIdx.x * 4 + (tid >> 6);
  const int d = tid & 63;
  const int s = w & (SEQ - 1);
  const size_t idx = (size_t)w * HD + d;

  float qg, qb, kg, kb;
  if (isf32) {
    qg = ((const float*)qgv)[d]; qb = ((const float*)qbv)[d];
    kg = ((const float*)kgv)[d]; kb = ((const float*)kbv)[d];
  } else {
    qg = bf2f(((const unsigned short*)qgv)[d]); qb = bf2f(((const unsigned short*)qbv)[d]);
    kg = bf2f(((const unsigned short*)kgv)[d]); kb = bf2f(((const unsigned short*)kbv)[d]);
  }

  float qv = Qb[idx], kv = Kb[idx];

  float mu = wave_sum64(qv) * (1.f / 64.f);
  float dq = qv - mu;
  float var = wave_sum64(dq * dq) * (1.f / 64.f);
  float qn = dq * rsqrtf(var + EPS) * qg + qb;

  mu = wave_sum64(kv) * (1.f / 64.f);
  float dk = kv - mu;
  var = wave_sum64(dk * dk) * (1.f / 64.f);
  float kn = dk * rsqrtf(var + EPS) * kg + kb;

  const float fr = (float)(d & 31) * (1.f / 32.f);
  const float inv_freq = expf(-fr * 9.210340371976184f);
  const float ang = (float)s * inv_freq;
  float sn, cs;
  sincosf(ang, &sn, &cs);  // sin first!
  const float sgn = (d < 32) ? -1.f : 1.f;
  const float qp = __shfl_xor(qn, 32);
  const float kp = __shfl_xor(kn, 32);
  const float qr = qn * cs + sgn * qp * sn;
  const float kr = kn * cs + sgn * kp * sn;

  Qb[idx] = qr * 0.125f;  // fold in D^-0.5
  Kb[idx] = kr;
}

// ---------------------------------------------------------------------------
// MFMA flash attention. Block = 256 thr = 4 waves; Q-tile 64 (16 rows/wave),
// K-tile 64. mfma_f32_16x16x32_bf16 layouts (HW-verified per guide):
//   A[m=lane&15][k=quad*8+j], B[k=quad*8+j][n=lane&15],
//   C/D[row=quad*4+reg][col=lane&15].
// QK^T: A=Q (regs), B=K from LDS Ks[key][dim] (b128, stride 72 -> 2-way=free).
// PV:   A=P via LDS round-trip Ps (C-layout -> A-layout), B=V from LDS
//       transposed Vt[dim][key] (b128). fp32 accum; online softmax per row.
// Q/K/V are fp32 in workspace; converted to bf16 at staging only.
// ---------------------------------------------------------------------------
__global__ __launch_bounds__(256)
void attn_mfma(const float* __restrict__ Q, const float* __restrict__ K,
               const float* __restrict__ V, float* __restrict__ O) {
  __shared__ unsigned short Ks[64][72];
  __shared__ unsigned short Vt[64][72];      // [dim][key]
  __shared__ unsigned short Ps[4][16][72];   // per-wave P tile

  const int tid  = threadIdx.x;
  const int wv   = tid >> 6;
  const int lane = tid & 63;
  const int l15  = lane & 15;
  const int quad = lane >> 4;
  const int bh = blockIdx.y;
  const int q0 = blockIdx.x * 64 + wv * 16;
  const size_t base = (size_t)bh * (SEQ * HD);

  // Q fragments (A-operand): row q0+l15, k = k0*32 + quad*8 + j
  bf16x8 qf[2];
  {
    const float* qrow = Q + base + (size_t)(q0 + l15) * HD;
#pragma unroll
    for (int k0 = 0; k0 < 2; ++k0) {
      float t[8];
      *(float4*)&t[0] = *(const float4*)&qrow[k0 * 32 + quad * 8];
      *(float4*)&t[4] = *(const float4*)&qrow[k0 * 32 + quad * 8 + 4];
#pragma unroll
      for (int j = 0; j < 8; ++j) qf[k0][j] = (short)f2bf(t[j]);
    }
  }

  f32x4 oacc[4];
#pragma unroll
  for (int nb = 0; nb < 4; ++nb) oacc[nb] = (f32x4){0.f, 0.f, 0.f, 0.f};
  float m_run[4] = {-1e30f, -1e30f, -1e30f, -1e30f};
  float l_run[4] = {0.f, 0.f, 0.f, 0.f};

  for (int kt = 0; kt < SEQ; kt += 64) {
    __syncthreads();
    // stage K-tile -> Ks[key][dim] and V-tile -> Vt[dim][key], bf16
    {
      const int key = tid >> 2;
      const int d0  = (tid & 3) * 16;
      const float* krow = K + base + (size_t)(kt + key) * HD + d0;
      const float* vrow = V + base + (size_t)(kt + key) * HD + d0;
#pragma unroll
      for (int i = 0; i < 4; ++i) {
        float4 kv4 = *(const float4*)&krow[i * 4];
        ushort4 kb;
        kb.x = f2bf(kv4.x); kb.y = f2bf(kv4.y);
        kb.z = f2bf(kv4.z); kb.w = f2bf(kv4.w);
        *(ushort4*)&Ks[key][d0 + i * 4] = kb;
        float4 vv4 = *(const float4*)&vrow[i * 4];
        Vt[d0 + i * 4 + 0][key] = f2bf(vv4.x);
        Vt[d0 + i * 4 + 1][key] = f2bf(vv4.y);
        Vt[d0 + i * 4 + 2][key] = f2bf(vv4.z);
        Vt[d0 + i * 4 + 3][key] = f2bf(vv4.w);
      }
    }
    __syncthreads();

    // S = Q K^T : 4 key-blocks of 16
    f32x4 sacc[4];
#pragma unroll
    for (int nb = 0; nb < 4; ++nb) sacc[nb] = (f32x4){0.f, 0.f, 0.f, 0.f};
#pragma unroll
    for (int nb = 0; nb < 4; ++nb)
#pragma unroll
      for (int k0 = 0; k0 < 2; ++k0) {
        bf16x8 bf = *(const bf16x8*)&Ks[nb * 16 + l15][k0 * 32 + quad * 8];
        sacc[nb] = __builtin_amdgcn_mfma_f32_16x16x32_bf16(qf[k0], bf, sacc[nb], 0, 0, 0);
      }

    // online softmax (row = quad*4 + r, cols across 16 lanes x 4 blocks)
    float alpha[4];
#pragma unroll
    for (int r = 0; r < 4; ++r) {
      float t = fmaxf(fmaxf(sacc[0][r], sacc[1][r]), fmaxf(sacc[2][r], sacc[3][r]));
      t = fmaxf(t, __shfl_xor(t, 1));
      t = fmaxf(t, __shfl_xor(t, 2));
      t = fmaxf(t, __shfl_xor(t, 4));
      t = fmaxf(t, __shfl_xor(t, 8));
      const float m_new = fmaxf(m_run[r], t);
      alpha[r] = __expf(m_run[r] - m_new);
      m_run[r] = m_new;
    }

    float lsum[4] = {0.f, 0.f, 0.f, 0.f};
#pragma unroll
    for (int nb = 0; nb < 4; ++nb)
#pragma unroll
      for (int r = 0; r < 4; ++r) {
        const float p = __expf(sacc[nb][r] - m_run[r]);
        lsum[r] += p;
        Ps[wv][quad * 4 + r][nb * 16 + l15] = f2bf(p);
      }
#pragma unroll
    for (int r = 0; r < 4; ++r) {
      float t = lsum[r];
      t += __shfl_xor(t, 1);
      t += __shfl_xor(t, 2);
      t += __shfl_xor(t, 4);
      t += __shfl_xor(t, 8);
      l_run[r] = l_run[r] * alpha[r] + t;
    }
#pragma unroll
    for (int nb = 0; nb < 4; ++nb) {
      oacc[nb][0] *= alpha[0]; oacc[nb][1] *= alpha[1];
      oacc[nb][2] *= alpha[2]; oacc[nb][3] *= alpha[3];
    }

    // PV: A = P (same-wave LDS round-trip; in-wave DS ordering suffices)
    bf16x8 pf[2];
#pragma unroll
    for (int k0 = 0; k0 < 2; ++k0)
      pf[k0] = *(const bf16x8*)&Ps[wv][l15][k0 * 32 + quad * 8];
#pragma unroll
    for (int nb = 0; nb < 4; ++nb)
#pragma unroll
      for (int k0 = 0; k0 < 2; ++k0) {
        bf16x8 vf = *(const bf16x8*)&Vt[nb * 16 + l15][k0 * 32 + quad * 8];
        oacc[nb] = __builtin_amdgcn_mfma_f32_16x16x32_bf16(pf[k0], vf, oacc[nb], 0, 0, 0);
      }
  }

  // epilogue: normalize, write fp32 attnout [B][S][DIM]
  const int b = bh >> 4, h = bh & 15;
  float inv_l[4];
#pragma unroll
  for (int r = 0; r < 4; ++r) inv_l[r] = 1.f / l_run[r];
#pragma unroll
  for (int r = 0; r < 4; ++r) {
    float* orow = O + ((size_t)(b * SEQ + q0 + quad * 4 + r)) * DIM + h * HD;
#pragma unroll
    for (int nb = 0; nb < 4; ++nb)
      orow[nb * 16 + l15] = oacc[nb][r] * inv_l[r];
  }
}

// ---------------------------------------------------------------------------
extern "C" void kernel_launch(void* const* d_in, const int* in_sizes, int n_in,
                              void* d_out, int out_size, void* d_ws, size_t ws_size,
                              hipStream_t stream) {
  const void* x      = d_in[0];
  const void* w_qkv  = d_in[1];
  const void* w_proj = d_in[2];
  const void* b_proj = d_in[3];
  const void* q_g    = d_in[4];
  const void* q_b    = d_in[5];
  const void* k_g    = d_in[6];
  const void* k_b    = d_in[7];

  const size_t PLANE = (size_t)BATCH * NH * SEQ * HD;
  float* qbuf = (float*)d_ws;
  float* kbuf = qbuf + PLANE;
  float* vbuf = qbuf + 2 * PLANE;
  float* attnout = qbuf + 3 * PLANE;
  int* flag = (int*)(qbuf + 4 * PLANE);

  hipLaunchKernelGGL(detect_dtype, dim3(1), dim3(256), 0, stream,
                     (const unsigned short*)w_qkv, flag);

  {
    dim3 grid((3 * DIM) / TS, (BATCH * SEQ) / TS);
    hipLaunchKernelGGL((gemm_nt<false, true>), grid, dim3(256), 0, stream,
                       x, w_qkv, (const void*)nullptr, (void*)qbuf,
                       BATCH * SEQ, 3 * DIM, DIM, flag);
  }
  {
    dim3 grid((BATCH * NH * SEQ) / 4);
    hipLaunchKernelGGL(ln_rope, grid, dim3(256), 0, stream,
                       qbuf, kbuf, q_g, q_b, k_g, k_b, flag);
  }
  {
    dim3 grid(SEQ / 64, BATCH * NH);
    hipLaunchKernelGGL(attn_mfma, grid, dim3(256), 0, stream,
                       qbuf, kbuf, vbuf, attnout);
  }
  {
    dim3 grid(DIM / TS, (BATCH * SEQ) / TS);
    hipLaunchKernelGGL((gemm_nt<true, false>), grid, dim3(256), 0, stream,
                       (const void*)attnout, w_proj, b_proj, d_out,
                       BATCH * SEQ, DIM, DIM, flag);
  }
}

// Round 5
// 337.119 us; speedup vs baseline: 4.1812x; 2.2163x over previous
//
#include <hip/hip_runtime.h>
#include <math.h>

#define DIM   1024
#define NH    16
#define HD    64
#define BATCH 2
#define SEQ   2048
#define EPS   1e-6f

typedef __attribute__((ext_vector_type(8))) short bf16x8;
typedef __attribute__((ext_vector_type(4))) float f32x4;

__device__ __forceinline__ float bf2f(unsigned short u) {
  return __uint_as_float(((unsigned int)u) << 16);
}
__device__ __forceinline__ unsigned short f2bf(float f) {
  unsigned int u = __float_as_uint(f);
  unsigned int r = (u + 0x7FFFu + ((u >> 16) & 1u)) >> 16;  // RNE
  return (unsigned short)r;
}

// async 16B/lane global->LDS DMA (m97: the 517->874 TF step)
__device__ __forceinline__ void async_copy16(const void* g, void* l) {
  __builtin_amdgcn_global_load_lds(
      (const __attribute__((address_space(1))) unsigned int*)g,
      (__attribute__((address_space(3))) unsigned int*)l, 16, 0, 0);
}

// ---------------------------------------------------------------------------
// Dtype detector (unchanged, passing): flag=1 -> fp32 inputs, 0 -> bf16.
// ---------------------------------------------------------------------------
__global__ void detect_dtype(const unsigned short* __restrict__ w, int* __restrict__ flag) {
  __shared__ int cnt;
  if (threadIdx.x == 0) cnt = 0;
  __syncthreads();
  int c = 0;
  for (int i = threadIdx.x; i < 4096; i += 256) {
    unsigned short u = w[i];
    if ((u & 0x7F80u) >= 0x3F80u) ++c;
  }
  atomicAdd(&cnt, c);
  __syncthreads();
  if (threadIdx.x == 0) *flag = (cnt >= 64) ? 1 : 0;
}

// ---------------------------------------------------------------------------
// Convert an input tensor (flag dtype) to packed bf16. n multiple of 8.
// ---------------------------------------------------------------------------
__global__ __launch_bounds__(256)
void convert_bf16(const void* __restrict__ src, unsigned short* __restrict__ dst,
                  int n, const int* __restrict__ flagp) {
  const bool isf32 = (*flagp != 0);
  const int i = (blockIdx.x * 256 + threadIdx.x) * 8;
  if (i >= n) return;
  if (isf32) {
    const float* s = (const float*)src + i;
    float4 a = *(const float4*)s;
    float4 b = *(const float4*)(s + 4);
    ushort4 lo, hi;
    lo.x = f2bf(a.x); lo.y = f2bf(a.y); lo.z = f2bf(a.z); lo.w = f2bf(a.w);
    hi.x = f2bf(b.x); hi.y = f2bf(b.y); hi.z = f2bf(b.z); hi.w = f2bf(b.w);
    *(ushort4*)&dst[i] = lo;
    *(ushort4*)&dst[i + 4] = hi;
  } else {
    *(uint4*)&dst[i] = *(const uint4*)((const unsigned short*)src + i);
  }
}

// ---------------------------------------------------------------------------
// MFMA GEMM: C[M,N] = A[M,K]*B[N,K]^T, A,B bf16. 128x128 tile, BK=32,
// 4 waves in 2x2 (64x64 each, 4x4 16x16x32 tiles). global_load_lds staging
// into unpadded As/Bs[row][32] bf16 (frag b128 reads: quad-offset 16B gives
// perfect 8-words/bank distribution). 16 MFMA + 8 ds_read_b128 per K-iter.
// STORE_QKV: scatter fp32 to q/k/v planes [3][B*H][S][HD].
// else: + bias (flag dtype), store to d_out in flag dtype.
// ---------------------------------------------------------------------------
template <bool STORE_QKV>
__global__ __launch_bounds__(256)
void gemm_mfma(const unsigned short* __restrict__ A, const unsigned short* __restrict__ B,
               const void* __restrict__ biasv, void* __restrict__ Cv,
               int M, int N, int K, const int* __restrict__ flagp) {
  __shared__ __attribute__((aligned(16))) unsigned short As[128 * 32];
  __shared__ __attribute__((aligned(16))) unsigned short Bs[128 * 32];

  const int tid  = threadIdx.x;
  const int wv   = tid >> 6;
  const int lane = tid & 63;
  const int l15  = lane & 15;
  const int quad = lane >> 4;
  const int wm = wv >> 1, wn = wv & 1;
  const int bm = blockIdx.y * 128;
  const int bn = blockIdx.x * 128;

  f32x4 acc[4][4];
#pragma unroll
  for (int i = 0; i < 4; ++i)
#pragma unroll
    for (int j = 0; j < 4; ++j) acc[i][j] = (f32x4){0.f, 0.f, 0.f, 0.f};

  // staging coords: thread -> (row = tid>>2 in [0,64), kseg = (tid&3)*8)
  const int srow = tid >> 2;
  const int kseg = (tid & 3) * 8;
  const unsigned short* Ag = A + (size_t)(bm + srow) * K + kseg;
  const unsigned short* Bg = B + (size_t)(bn + srow) * K + kseg;
  unsigned short* AsW = &As[wv * 512];  // wave-uniform LDS base (lane*16B implicit)
  unsigned short* BsW = &Bs[wv * 512];

  for (int k0 = 0; k0 < K; k0 += 32) {
    __syncthreads();
    async_copy16(Ag + k0, AsW);
    async_copy16(Ag + (size_t)64 * K + k0, AsW + 2048);
    async_copy16(Bg + k0, BsW);
    async_copy16(Bg + (size_t)64 * K + k0, BsW + 2048);
    __syncthreads();  // drains vmcnt (global_load_lds) + barrier

    bf16x8 af[4], bf[4];
#pragma unroll
    for (int mt = 0; mt < 4; ++mt)
      af[mt] = *(const bf16x8*)&As[(wm * 64 + mt * 16 + l15) * 32 + quad * 8];
#pragma unroll
    for (int nt = 0; nt < 4; ++nt)
      bf[nt] = *(const bf16x8*)&Bs[(wn * 64 + nt * 16 + l15) * 32 + quad * 8];
#pragma unroll
    for (int mt = 0; mt < 4; ++mt)
#pragma unroll
      for (int nt = 0; nt < 4; ++nt)
        acc[mt][nt] = __builtin_amdgcn_mfma_f32_16x16x32_bf16(af[mt], bf[nt], acc[mt][nt], 0, 0, 0);
  }

  const bool isf32 = (*flagp != 0);
#pragma unroll
  for (int mt = 0; mt < 4; ++mt) {
#pragma unroll
    for (int rr = 0; rr < 4; ++rr) {
      const int r = bm + wm * 64 + mt * 16 + quad * 4 + rr;
#pragma unroll
      for (int nt = 0; nt < 4; ++nt) {
        const int c = bn + wn * 64 + nt * 16 + l15;
        const float v = acc[mt][nt][rr];
        if (STORE_QKV) {
          const int b = r >> 11, s = r & 2047;
          const int j = c >> 10, h = (c >> 6) & 15, d0 = c & 63;
          float* C = (float*)Cv;
          C[(size_t)j * (BATCH * NH * SEQ * HD) +
            ((size_t)((b << 4) + h) * SEQ + s) * HD + d0] = v;
        } else {
          const float bias_c = isf32 ? ((const float*)biasv)[c]
                                     : bf2f(((const unsigned short*)biasv)[c]);
          const float o = v + bias_c;
          if (isf32) ((float*)Cv)[(size_t)r * N + c] = o;
          else       ((unsigned short*)Cv)[(size_t)r * N + c] = f2bf(o);
        }
      }
    }
  }
}

// ---------------------------------------------------------------------------
// LayerNorm + RoPE (unchanged, passing).
// ---------------------------------------------------------------------------
__device__ __forceinline__ float wave_sum64(float v) {
#pragma unroll
  for (int o = 32; o; o >>= 1) v += __shfl_xor(v, o);
  return v;
}

__global__ __launch_bounds__(256)
void ln_rope(float* __restrict__ Qb, float* __restrict__ Kb,
             const void* __restrict__ qgv, const void* __restrict__ qbv,
             const void* __restrict__ kgv, const void* __restrict__ kbv,
             const int* __restrict__ flagp) {
  const bool isf32 = (*flagp != 0);
  const int tid = threadIdx.x;
  const int w = blockIdx.x * 4 + (tid >> 6);
  const int d = tid & 63;
  const int s = w & (SEQ - 1);
  const size_t idx = (size_t)w * HD + d;

  float qg, qb, kg, kb;
  if (isf32) {
    qg = ((const float*)qgv)[d]; qb = ((const float*)qbv)[d];
    kg = ((const float*)kgv)[d]; kb = ((const float*)kbv)[d];
  } else {
    qg = bf2f(((const unsigned short*)qgv)[d]); qb = bf2f(((const unsigned short*)qbv)[d]);
    kg = bf2f(((const unsigned short*)kgv)[d]); kb = bf2f(((const unsigned short*)kbv)[d]);
  }

  float qv = Qb[idx], kv = Kb[idx];

  float mu = wave_sum64(qv) * (1.f / 64.f);
  float dq = qv - mu;
  float var = wave_sum64(dq * dq) * (1.f / 64.f);
  float qn = dq * rsqrtf(var + EPS) * qg + qb;

  mu = wave_sum64(kv) * (1.f / 64.f);
  float dk = kv - mu;
  var = wave_sum64(dk * dk) * (1.f / 64.f);
  float kn = dk * rsqrtf(var + EPS) * kg + kb;

  const float fr = (float)(d & 31) * (1.f / 32.f);
  const float inv_freq = expf(-fr * 9.210340371976184f);
  const float ang = (float)s * inv_freq;
  float sn, cs;
  sincosf(ang, &sn, &cs);  // sin first!
  const float sgn = (d < 32) ? -1.f : 1.f;
  const float qp = __shfl_xor(qn, 32);
  const float kp = __shfl_xor(kn, 32);
  const float qr = qn * cs + sgn * qp * sn;
  const float kr = kn * cs + sgn * kp * sn;

  Qb[idx] = qr * 0.125f;  // fold in D^-0.5
  Kb[idx] = kr;
}

// ---------------------------------------------------------------------------
// MFMA flash attention (passing round-4 core; epilogue now emits bf16 so the
// output projection consumes it natively).
// ---------------------------------------------------------------------------
__global__ __launch_bounds__(256)
void attn_mfma(const float* __restrict__ Q, const float* __restrict__ K,
               const float* __restrict__ V, unsigned short* __restrict__ O) {
  __shared__ unsigned short Ks[64][72];
  __shared__ unsigned short Vt[64][72];
  __shared__ unsigned short Ps[4][16][72];

  const int tid  = threadIdx.x;
  const int wv   = tid >> 6;
  const int lane = tid & 63;
  const int l15  = lane & 15;
  const int quad = lane >> 4;
  const int bh = blockIdx.y;
  const int q0 = blockIdx.x * 64 + wv * 16;
  const size_t base = (size_t)bh * (SEQ * HD);

  bf16x8 qf[2];
  {
    const float* qrow = Q + base + (size_t)(q0 + l15) * HD;
#pragma unroll
    for (int k0 = 0; k0 < 2; ++k0) {
      float t[8];
      *(float4*)&t[0] = *(const float4*)&qrow[k0 * 32 + quad * 8];
      *(float4*)&t[4] = *(const float4*)&qrow[k0 * 32 + quad * 8 + 4];
#pragma unroll
      for (int j = 0; j < 8; ++j) qf[k0][j] = (short)f2bf(t[j]);
    }
  }

  f32x4 oacc[4];
#pragma unroll
  for (int nb = 0; nb < 4; ++nb) oacc[nb] = (f32x4){0.f, 0.f, 0.f, 0.f};
  float m_run[4] = {-1e30f, -1e30f, -1e30f, -1e30f};
  float l_run[4] = {0.f, 0.f, 0.f, 0.f};

  for (int kt = 0; kt < SEQ; kt += 64) {
    __syncthreads();
    {
      const int key = tid >> 2;
      const int d0  = (tid & 3) * 16;
      const float* krow = K + base + (size_t)(kt + key) * HD + d0;
      const float* vrow = V + base + (size_t)(kt + key) * HD + d0;
#pragma unroll
      for (int i = 0; i < 4; ++i) {
        float4 kv4 = *(const float4*)&krow[i * 4];
        ushort4 kb;
        kb.x = f2bf(kv4.x); kb.y = f2bf(kv4.y);
        kb.z = f2bf(kv4.z); kb.w = f2bf(kv4.w);
        *(ushort4*)&Ks[key][d0 + i * 4] = kb;
        float4 vv4 = *(const float4*)&vrow[i * 4];
        Vt[d0 + i * 4 + 0][key] = f2bf(vv4.x);
        Vt[d0 + i * 4 + 1][key] = f2bf(vv4.y);
        Vt[d0 + i * 4 + 2][key] = f2bf(vv4.z);
        Vt[d0 + i * 4 + 3][key] = f2bf(vv4.w);
      }
    }
    __syncthreads();

    f32x4 sacc[4];
#pragma unroll
    for (int nb = 0; nb < 4; ++nb) sacc[nb] = (f32x4){0.f, 0.f, 0.f, 0.f};
#pragma unroll
    for (int nb = 0; nb < 4; ++nb)
#pragma unroll
      for (int k0 = 0; k0 < 2; ++k0) {
        bf16x8 bf = *(const bf16x8*)&Ks[nb * 16 + l15][k0 * 32 + quad * 8];
        sacc[nb] = __builtin_amdgcn_mfma_f32_16x16x32_bf16(qf[k0], bf, sacc[nb], 0, 0, 0);
      }

    float alpha[4];
#pragma unroll
    for (int r = 0; r < 4; ++r) {
      float t = fmaxf(fmaxf(sacc[0][r], sacc[1][r]), fmaxf(sacc[2][r], sacc[3][r]));
      t = fmaxf(t, __shfl_xor(t, 1));
      t = fmaxf(t, __shfl_xor(t, 2));
      t = fmaxf(t, __shfl_xor(t, 4));
      t = fmaxf(t, __shfl_xor(t, 8));
      const float m_new = fmaxf(m_run[r], t);
      alpha[r] = __expf(m_run[r] - m_new);
      m_run[r] = m_new;
    }

    float lsum[4] = {0.f, 0.f, 0.f, 0.f};
#pragma unroll
    for (int nb = 0; nb < 4; ++nb)
#pragma unroll
      for (int r = 0; r < 4; ++r) {
        const float p = __expf(sacc[nb][r] - m_run[r]);
        lsum[r] += p;
        Ps[wv][quad * 4 + r][nb * 16 + l15] = f2bf(p);
      }
#pragma unroll
    for (int r = 0; r < 4; ++r) {
      float t = lsum[r];
      t += __shfl_xor(t, 1);
      t += __shfl_xor(t, 2);
      t += __shfl_xor(t, 4);
      t += __shfl_xor(t, 8);
      l_run[r] = l_run[r] * alpha[r] + t;
    }
#pragma unroll
    for (int nb = 0; nb < 4; ++nb) {
      oacc[nb][0] *= alpha[0]; oacc[nb][1] *= alpha[1];
      oacc[nb][2] *= alpha[2]; oacc[nb][3] *= alpha[3];
    }

    bf16x8 pf[2];
#pragma unroll
    for (int k0 = 0; k0 < 2; ++k0)
      pf[k0] = *(const bf16x8*)&Ps[wv][l15][k0 * 32 + quad * 8];
#pragma unroll
    for (int nb = 0; nb < 4; ++nb)
#pragma unroll
      for (int k0 = 0; k0 < 2; ++k0) {
        bf16x8 vf = *(const bf16x8*)&Vt[nb * 16 + l15][k0 * 32 + quad * 8];
        oacc[nb] = __builtin_amdgcn_mfma_f32_16x16x32_bf16(pf[k0], vf, oacc[nb], 0, 0, 0);
      }
  }

  // epilogue: normalize, write bf16 attnout [B][S][DIM]
  const int b = bh >> 4, h = bh & 15;
#pragma unroll
  for (int r = 0; r < 4; ++r) {
    const float inv_l = 1.f / l_run[r];
    unsigned short* orow = O + ((size_t)(b * SEQ + q0 + quad * 4 + r)) * DIM + h * HD;
#pragma unroll
    for (int nb = 0; nb < 4; ++nb)
      orow[nb * 16 + l15] = f2bf(oacc[nb][r] * inv_l);
  }
}

// ---------------------------------------------------------------------------
extern "C" void kernel_launch(void* const* d_in, const int* in_sizes, int n_in,
                              void* d_out, int out_size, void* d_ws, size_t ws_size,
                              hipStream_t stream) {
  const void* x      = d_in[0];
  const void* w_qkv  = d_in[1];
  const void* w_proj = d_in[2];
  const void* b_proj = d_in[3];
  const void* q_g    = d_in[4];
  const void* q_b    = d_in[5];
  const void* k_g    = d_in[6];
  const void* k_b    = d_in[7];

  const size_t PLANE = (size_t)BATCH * NH * SEQ * HD;  // 4 Mi elems
  const int NX = BATCH * SEQ * DIM;                    // 4 Mi
  const int NWQ = 3 * DIM * DIM;                       // 3 Mi
  const int NWP = DIM * DIM;                           // 1 Mi

  float* qbuf = (float*)d_ws;                          // 16 MB
  float* kbuf = qbuf + PLANE;                          // 16 MB
  float* vbuf = qbuf + 2 * PLANE;                      // 16 MB
  unsigned short* xb_attn = (unsigned short*)(qbuf + 3 * PLANE);  // 8 MB shared: xb then attnout
  unsigned short* wqb = xb_attn + PLANE;               // 6 MB
  unsigned short* wpb = wqb + NWQ;                     // 2 MB
  int* flag = (int*)(wpb + NWP);                       // 4 B @ 64 MB

  hipLaunchKernelGGL(detect_dtype, dim3(1), dim3(256), 0, stream,
                     (const unsigned short*)w_qkv, flag);

  hipLaunchKernelGGL(convert_bf16, dim3(NX / 8 / 256), dim3(256), 0, stream,
                     x, xb_attn, NX, flag);
  hipLaunchKernelGGL(convert_bf16, dim3(NWQ / 8 / 256), dim3(256), 0, stream,
                     w_qkv, wqb, NWQ, flag);
  hipLaunchKernelGGL(convert_bf16, dim3(NWP / 8 / 256), dim3(256), 0, stream,
                     w_proj, wpb, NWP, flag);

  // 1) QKV projection (MFMA), permuted fp32 store into planes
  {
    dim3 grid((3 * DIM) / 128, (BATCH * SEQ) / 128);
    hipLaunchKernelGGL((gemm_mfma<true>), grid, dim3(256), 0, stream,
                       xb_attn, wqb, (const void*)nullptr, (void*)qbuf,
                       BATCH * SEQ, 3 * DIM, DIM, flag);
  }
  // 2) LayerNorm + RoPE
  {
    dim3 grid((BATCH * NH * SEQ) / 4);
    hipLaunchKernelGGL(ln_rope, grid, dim3(256), 0, stream,
                       qbuf, kbuf, q_g, q_b, k_g, k_b, flag);
  }
  // 3) flash attention -> bf16 attnout (reuses xb slot; xb dead by now)
  {
    dim3 grid(SEQ / 64, BATCH * NH);
    hipLaunchKernelGGL(attn_mfma, grid, dim3(256), 0, stream,
                       qbuf, kbuf, vbuf, xb_attn);
  }
  // 4) output projection (MFMA) + bias -> d_out (flag dtype)
  {
    dim3 grid(DIM / 128, (BATCH * SEQ) / 128);
    hipLaunchKernelGGL((gemm_mfma<false>), grid, dim3(256), 0, stream,
                       xb_attn, wpb, b_proj, d_out,
                       BATCH * SEQ, DIM, DIM, flag);
  }
}

// Round 6
// 266.710 us; speedup vs baseline: 5.2850x; 1.2640x over previous
//
#include <hip/hip_runtime.h>
#include <math.h>

#define DIM   1024
#define NH    16
#define HD    64
#define BATCH 2
#define SEQ   2048
#define EPS   1e-6f

typedef __attribute__((ext_vector_type(8))) short bf16x8;
typedef __attribute__((ext_vector_type(4))) float f32x4;

__device__ __forceinline__ float bf2f(unsigned short u) {
  return __uint_as_float(((unsigned int)u) << 16);
}
__device__ __forceinline__ unsigned short f2bf(float f) {
  unsigned int u = __float_as_uint(f);
  unsigned int r = (u + 0x7FFFu + ((u >> 16) & 1u)) >> 16;  // RNE
  return (unsigned short)r;
}
// pack two fp32 -> two bf16 by truncation (cheap; P-normalization cancels bias)
__device__ __forceinline__ unsigned int pack_bf16_trunc(float p0, float p1) {
  return (__float_as_uint(p1) & 0xFFFF0000u) | (__float_as_uint(p0) >> 16);
}

// async 16B/lane global->LDS DMA (m97 path)
__device__ __forceinline__ void async_copy16(const void* g, void* l) {
  __builtin_amdgcn_global_load_lds(
      (const __attribute__((address_space(1))) unsigned int*)g,
      (__attribute__((address_space(3))) unsigned int*)l, 16, 0, 0);
}

// ---------------------------------------------------------------------------
// Dtype detector (unchanged, passing): flag=1 -> fp32 inputs, 0 -> bf16.
// ---------------------------------------------------------------------------
__global__ void detect_dtype(const unsigned short* __restrict__ w, int* __restrict__ flag) {
  __shared__ int cnt;
  if (threadIdx.x == 0) cnt = 0;
  __syncthreads();
  int c = 0;
  for (int i = threadIdx.x; i < 4096; i += 256) {
    unsigned short u = w[i];
    if ((u & 0x7F80u) >= 0x3F80u) ++c;
  }
  atomicAdd(&cnt, c);
  __syncthreads();
  if (threadIdx.x == 0) *flag = (cnt >= 64) ? 1 : 0;
}

// ---------------------------------------------------------------------------
// Convert input tensor (flag dtype) -> packed bf16. n multiple of 8.
// ---------------------------------------------------------------------------
__global__ __launch_bounds__(256)
void convert_bf16(const void* __restrict__ src, unsigned short* __restrict__ dst,
                  int n, const int* __restrict__ flagp) {
  const bool isf32 = (*flagp != 0);
  const int i = (blockIdx.x * 256 + threadIdx.x) * 8;
  if (i >= n) return;
  if (isf32) {
    const float* s = (const float*)src + i;
    float4 a = *(const float4*)s;
    float4 b = *(const float4*)(s + 4);
    ushort4 lo, hi;
    lo.x = f2bf(a.x); lo.y = f2bf(a.y); lo.z = f2bf(a.z); lo.w = f2bf(a.w);
    hi.x = f2bf(b.x); hi.y = f2bf(b.y); hi.z = f2bf(b.z); hi.w = f2bf(b.w);
    *(ushort4*)&dst[i] = lo;
    *(ushort4*)&dst[i + 4] = hi;
  } else {
    *(uint4*)&dst[i] = *(const uint4*)((const unsigned short*)src + i);
  }
}

__device__ __forceinline__ float ld_param(const void* p, bool isf32, int idx) {
  return isf32 ? ((const float*)p)[idx] : bf2f(((const unsigned short*)p)[idx]);
}

// ---------------------------------------------------------------------------
// QKV GEMM with fused LayerNorm+RoPE epilogue.
// C[M,3072] = x[M,1024]*w_qkv^T. 128x128 tile, BK=32, 4 waves 2x2, m97 core.
// Block col-range is entirely Q (type0), K (1) or V (2); each wave owns ONE
// head (64 cols): LN reduce = 3 adds + 4 shfl per row; RoPE partner d^32 is
// in-lane at nt^2. Emits bf16 planes Qb/Kb/Vb [B*H][S][HD] (Q scaled 0.125).
// ---------------------------------------------------------------------------
__global__ __launch_bounds__(256)
void gemm_qkv(const unsigned short* __restrict__ A, const unsigned short* __restrict__ B,
              unsigned short* __restrict__ Qb, unsigned short* __restrict__ Kb,
              unsigned short* __restrict__ Vb,
              const void* __restrict__ qg, const void* __restrict__ qbe,
              const void* __restrict__ kg, const void* __restrict__ kbe,
              const int* __restrict__ flagp) {
  __shared__ __attribute__((aligned(16))) unsigned short As[128 * 32];
  __shared__ __attribute__((aligned(16))) unsigned short Bs[128 * 32];

  const int K = DIM;
  const int tid  = threadIdx.x;
  const int wv   = tid >> 6;
  const int lane = tid & 63;
  const int l15  = lane & 15;
  const int quad = lane >> 4;
  const int wm = wv >> 1, wn = wv & 1;
  const int bm = blockIdx.y * 128;
  const int bn = blockIdx.x * 128;

  f32x4 acc[4][4];
#pragma unroll
  for (int i = 0; i < 4; ++i)
#pragma unroll
    for (int j = 0; j < 4; ++j) acc[i][j] = (f32x4){0.f, 0.f, 0.f, 0.f};

  const int srow = tid >> 2;
  const int kseg = (tid & 3) * 8;
  const unsigned short* Ag = A + (size_t)(bm + srow) * K + kseg;
  const unsigned short* Bg = B + (size_t)(bn + srow) * K + kseg;
  unsigned short* AsW = &As[wv * 512];
  unsigned short* BsW = &Bs[wv * 512];

  for (int k0 = 0; k0 < K; k0 += 32) {
    __syncthreads();
    async_copy16(Ag + k0, AsW);
    async_copy16(Ag + (size_t)64 * K + k0, AsW + 2048);
    async_copy16(Bg + k0, BsW);
    async_copy16(Bg + (size_t)64 * K + k0, BsW + 2048);
    __syncthreads();

    bf16x8 af[4], bf[4];
#pragma unroll
    for (int mt = 0; mt < 4; ++mt)
      af[mt] = *(const bf16x8*)&As[(wm * 64 + mt * 16 + l15) * 32 + quad * 8];
#pragma unroll
    for (int nt = 0; nt < 4; ++nt)
      bf[nt] = *(const bf16x8*)&Bs[(wn * 64 + nt * 16 + l15) * 32 + quad * 8];
#pragma unroll
    for (int mt = 0; mt < 4; ++mt)
#pragma unroll
      for (int nt = 0; nt < 4; ++nt)
        acc[mt][nt] = __builtin_amdgcn_mfma_f32_16x16x32_bf16(af[mt], bf[nt], acc[mt][nt], 0, 0, 0);
  }

  // ----- fused epilogue -----
  const bool isf32 = (*flagp != 0);
  const int type = bn >> 10;                 // 0=Q 1=K 2=V
  const int h = ((bn & 1023) >> 6) + wn;     // head for this wave
  unsigned short* plane = (type == 0) ? Qb : (type == 1) ? Kb : Vb;

  if (type == 2) {
#pragma unroll
    for (int mt = 0; mt < 4; ++mt)
#pragma unroll
      for (int rr = 0; rr < 4; ++rr) {
        const int r = bm + wm * 64 + mt * 16 + quad * 4 + rr;
        const int b = r >> 11, s = r & 2047;
        unsigned short* row = plane + (((size_t)(b * NH + h) * SEQ + s) * HD);
#pragma unroll
        for (int nt = 0; nt < 4; ++nt)
          row[nt * 16 + l15] = f2bf(acc[mt][nt][rr]);
      }
    return;
  }

  // gamma/beta for this lane's 4 d-values (d = nt*16+l15)
  const void* gp = (type == 0) ? qg : kg;
  const void* bp = (type == 0) ? qbe : kbe;
  float gam[4], bet[4];
#pragma unroll
  for (int nt = 0; nt < 4; ++nt) {
    gam[nt] = ld_param(gp, isf32, nt * 16 + l15);
    bet[nt] = ld_param(bp, isf32, nt * 16 + l15);
  }
  // RoPE inv-freqs for this lane: d%32 = l15 (nt even) or 16+l15 (nt odd)
  const float invf_e = expf(-((float)l15 * (1.f / 32.f)) * 9.210340371976184f);
  const float invf_o = expf(-((float)(16 + l15) * (1.f / 32.f)) * 9.210340371976184f);
  const float scale = (type == 0) ? 0.125f : 1.f;

#pragma unroll
  for (int mt = 0; mt < 4; ++mt)
#pragma unroll
    for (int rr = 0; rr < 4; ++rr) {
      const int r = bm + wm * 64 + mt * 16 + quad * 4 + rr;
      const int b = r >> 11, s = r & 2047;
      // LayerNorm over the head's 64 outputs (4 nt x 16 lanes)
      float sum = acc[mt][0][rr] + acc[mt][1][rr] + acc[mt][2][rr] + acc[mt][3][rr];
      sum += __shfl_xor(sum, 1); sum += __shfl_xor(sum, 2);
      sum += __shfl_xor(sum, 4); sum += __shfl_xor(sum, 8);
      const float mu = sum * (1.f / 64.f);
      float vs = 0.f;
#pragma unroll
      for (int nt = 0; nt < 4; ++nt) {
        const float d = acc[mt][nt][rr] - mu;
        vs += d * d;
      }
      vs += __shfl_xor(vs, 1); vs += __shfl_xor(vs, 2);
      vs += __shfl_xor(vs, 4); vs += __shfl_xor(vs, 8);
      const float rs = rsqrtf(vs * (1.f / 64.f) + EPS);
      float xn[4];
#pragma unroll
      for (int nt = 0; nt < 4; ++nt)
        xn[nt] = (acc[mt][nt][rr] - mu) * rs * gam[nt] + bet[nt];
      // RoPE: pairs (nt, nt^2) share angle; sincosf(x, &sin, &cos)
      float sn0, cs0, sn1, cs1;
      sincosf((float)s * invf_e, &sn0, &cs0);
      sincosf((float)s * invf_o, &sn1, &cs1);
      float ro[4];
      ro[0] = xn[0] * cs0 - xn[2] * sn0;
      ro[2] = xn[2] * cs0 + xn[0] * sn0;
      ro[1] = xn[1] * cs1 - xn[3] * sn1;
      ro[3] = xn[3] * cs1 + xn[1] * sn1;
      unsigned short* row = plane + (((size_t)(b * NH + h) * SEQ + s) * HD);
#pragma unroll
      for (int nt = 0; nt < 4; ++nt)
        row[nt * 16 + l15] = f2bf(ro[nt] * scale);
    }
}

// ---------------------------------------------------------------------------
// V transpose: Vb [BH][S][HD] bf16 -> VbT [BH][HD][S] bf16. 64x64 LDS tile.
// ---------------------------------------------------------------------------
__global__ __launch_bounds__(256)
void transpose_v(const unsigned short* __restrict__ Vb, unsigned short* __restrict__ VbT) {
  __shared__ unsigned short L[64][72];
  const int bh = blockIdx.y;
  const int s0 = blockIdx.x * 64;
  const int t = threadIdx.x;
  const int r = t >> 2;
  const int c = (t & 3) * 16;
  const unsigned short* src = Vb + ((size_t)bh * SEQ + s0 + r) * HD + c;
  *(uint4*)&L[r][c]     = *(const uint4*)&src[0];
  *(uint4*)&L[r][c + 8] = *(const uint4*)&src[8];
  __syncthreads();
  unsigned short tmp[16];
#pragma unroll
  for (int i = 0; i < 16; ++i) tmp[i] = L[c + i][r];
  unsigned short* dst = VbT + ((size_t)bh * HD + r) * SEQ + s0 + c;
  *(uint4*)&dst[0] = *(const uint4*)&tmp[0];
  *(uint4*)&dst[8] = *(const uint4*)&tmp[8];
}

// ---------------------------------------------------------------------------
// Flash attention in TRANSPOSED score space. Q-tile 128 (4 waves x 32 rows),
// K-tile 64. S^T = K Q^T (A=K frags from LDS, B=Q frags from global regs);
// P^T exits C-layout with 4 consecutive keys/lane -> packed ds_write_b64;
// O^T = V^T P^T (A=V^T b128, B=P^T b128). Row state (m,alpha) is per-lane
// (qrow=l15): max reduce = 2 shfl. l accumulated via ones-A MFMA through the
// same alpha rescale (no sum-reduce, normalization consistent with trunc-P).
// K/V staged via global_load_lds into split [64][32] sub-tiles (conflict-free).
// ---------------------------------------------------------------------------
__global__ __launch_bounds__(256)
void attn_mfma2(const unsigned short* __restrict__ Qb, const unsigned short* __restrict__ Kb,
                const unsigned short* __restrict__ VbT, unsigned short* __restrict__ O) {
  __shared__ __attribute__((aligned(16))) unsigned short Ks2[2][64][32];
  __shared__ __attribute__((aligned(16))) unsigned short Vt2[2][64][32];
  __shared__ __attribute__((aligned(16))) unsigned short PsT[4][32][72];

  const int tid  = threadIdx.x;
  const int wv   = tid >> 6;
  const int lane = tid & 63;
  const int l15  = lane & 15;
  const int quad = lane >> 4;
  const int bh = blockIdx.y;
  const int q0 = blockIdx.x * 128;
  const size_t base  = (size_t)bh * (SEQ * HD);  // [key][dim] plane
  const size_t baseT = (size_t)bh * (HD * SEQ);  // [dim][key] plane

  // Q^T B-frags from global: qf[mt][k0]: qrow = q0+wv*32+mt*16+l15, dims k0*32+quad*8
  bf16x8 qf[2][2];
#pragma unroll
  for (int mt = 0; mt < 2; ++mt)
#pragma unroll
    for (int k0 = 0; k0 < 2; ++k0)
      qf[mt][k0] = *(const bf16x8*)&Qb[base + (size_t)(q0 + wv * 32 + mt * 16 + l15) * HD + k0 * 32 + quad * 8];

  bf16x8 ones;
#pragma unroll
  for (int j = 0; j < 8; ++j) ones[j] = (short)0x3F80;  // bf16 1.0

  f32x4 oaccT[4][2];  // [nb(dim-block)][mt]: row=dim nb*16+quad*4+reg, col=qrow l15
  f32x4 ol[2];        // l accumulator (all regs equal)
#pragma unroll
  for (int nb = 0; nb < 4; ++nb)
#pragma unroll
    for (int mt = 0; mt < 2; ++mt) oaccT[nb][mt] = (f32x4){0.f, 0.f, 0.f, 0.f};
  ol[0] = (f32x4){0.f, 0.f, 0.f, 0.f};
  ol[1] = (f32x4){0.f, 0.f, 0.f, 0.f};
  float m_run[2] = {-1e30f, -1e30f};

  // staging source pointers (per-lane), wave-uniform LDS dests
  const unsigned short* srcK = Kb + base + (size_t)(wv * 16 + (lane >> 2)) * HD + (lane & 3) * 8;
  const unsigned short* srcV = VbT + baseT + (size_t)(wv * 16 + (lane >> 2)) * SEQ + (lane & 3) * 8;

  for (int kt = 0; kt < SEQ; kt += 64) {
    __syncthreads();
    async_copy16(srcK + (size_t)kt * HD,      &Ks2[0][wv * 16][0]);
    async_copy16(srcK + (size_t)kt * HD + 32, &Ks2[1][wv * 16][0]);
    async_copy16(srcV + kt,                   &Vt2[0][wv * 16][0]);
    async_copy16(srcV + kt + 32,              &Vt2[1][wv * 16][0]);
    __syncthreads();

    // S^T[key][qrow]
    f32x4 st[4][2];
#pragma unroll
    for (int nb = 0; nb < 4; ++nb)
#pragma unroll
      for (int mt = 0; mt < 2; ++mt) st[nb][mt] = (f32x4){0.f, 0.f, 0.f, 0.f};
#pragma unroll
    for (int k0 = 0; k0 < 2; ++k0)
#pragma unroll
      for (int nb = 0; nb < 4; ++nb) {
        bf16x8 kf = *(const bf16x8*)&Ks2[k0][nb * 16 + l15][quad * 8];
#pragma unroll
        for (int mt = 0; mt < 2; ++mt)
          st[nb][mt] = __builtin_amdgcn_mfma_f32_16x16x32_bf16(kf, qf[mt][k0], st[nb][mt], 0, 0, 0);
      }

    // online softmax per lane (qrow = mt*16+l15), keys in-lane + cross-quad
#pragma unroll
    for (int mt = 0; mt < 2; ++mt) {
      float t = st[0][mt][0];
#pragma unroll
      for (int nb = 0; nb < 4; ++nb)
#pragma unroll
        for (int r = 0; r < 4; ++r) t = fmaxf(t, st[nb][mt][r]);
      t = fmaxf(t, __shfl_xor(t, 16));
      t = fmaxf(t, __shfl_xor(t, 32));
      const float m_new = fmaxf(m_run[mt], t);
      const float al = __expf(m_run[mt] - m_new);
      m_run[mt] = m_new;
#pragma unroll
      for (int nb = 0; nb < 4; ++nb) oaccT[nb][mt] *= al;
      ol[mt] *= al;
      // P^T: exp + truncation-pack, 4 consecutive keys per lane -> b64 store
#pragma unroll
      for (int nb = 0; nb < 4; ++nb) {
        const float p0 = __expf(st[nb][mt][0] - m_new);
        const float p1 = __expf(st[nb][mt][1] - m_new);
        const float p2 = __expf(st[nb][mt][2] - m_new);
        const float p3 = __expf(st[nb][mt][3] - m_new);
        uint2 pk;
        pk.x = pack_bf16_trunc(p0, p1);
        pk.y = pack_bf16_trunc(p2, p3);
        *(uint2*)&PsT[wv][mt * 16 + l15][nb * 16 + quad * 4] = pk;
      }
    }

    // O^T += V^T P^T ; l += 1 . P^T (same-wave LDS round-trip, no barrier)
#pragma unroll
    for (int k0 = 0; k0 < 2; ++k0) {
      bf16x8 pf0 = *(const bf16x8*)&PsT[wv][0 * 16 + l15][k0 * 32 + quad * 8];
      bf16x8 pf1 = *(const bf16x8*)&PsT[wv][1 * 16 + l15][k0 * 32 + quad * 8];
      ol[0] = __builtin_amdgcn_mfma_f32_16x16x32_bf16(ones, pf0, ol[0], 0, 0, 0);
      ol[1] = __builtin_amdgcn_mfma_f32_16x16x32_bf16(ones, pf1, ol[1], 0, 0, 0);
#pragma unroll
      for (int nb = 0; nb < 4; ++nb) {
        bf16x8 vf = *(const bf16x8*)&Vt2[k0][nb * 16 + l15][quad * 8];
        oaccT[nb][0] = __builtin_amdgcn_mfma_f32_16x16x32_bf16(vf, pf0, oaccT[nb][0], 0, 0, 0);
        oaccT[nb][1] = __builtin_amdgcn_mfma_f32_16x16x32_bf16(vf, pf1, oaccT[nb][1], 0, 0, 0);
      }
    }
  }

  // epilogue: O^T -> attnout [B][S][DIM] bf16 (4 consecutive dims/lane -> 8B stores)
  const int b = bh >> 4, h = bh & 15;
#pragma unroll
  for (int mt = 0; mt < 2; ++mt) {
    const float inv = 1.f / ol[mt][0];
    const int qrow = q0 + wv * 32 + mt * 16 + l15;
    unsigned short* orow = O + ((size_t)(b * SEQ + qrow)) * DIM + h * HD;
#pragma unroll
    for (int nb = 0; nb < 4; ++nb) {
      uint2 pk;
      pk.x = ((unsigned int)f2bf(oaccT[nb][mt][1] * inv) << 16) | f2bf(oaccT[nb][mt][0] * inv);
      pk.y = ((unsigned int)f2bf(oaccT[nb][mt][3] * inv) << 16) | f2bf(oaccT[nb][mt][2] * inv);
      *(uint2*)&orow[nb * 16 + quad * 4] = pk;
    }
  }
}

// ---------------------------------------------------------------------------
// Output projection (round-5 proven core): C = A[M,K]*B[N,K]^T + bias.
// ---------------------------------------------------------------------------
__global__ __launch_bounds__(256)
void gemm_out(const unsigned short* __restrict__ A, const unsigned short* __restrict__ B,
              const void* __restrict__ biasv, void* __restrict__ Cv,
              int M, int N, int K, const int* __restrict__ flagp) {
  __shared__ __attribute__((aligned(16))) unsigned short As[128 * 32];
  __shared__ __attribute__((aligned(16))) unsigned short Bs[128 * 32];

  const int tid  = threadIdx.x;
  const int wv   = tid >> 6;
  const int lane = tid & 63;
  const int l15  = lane & 15;
  const int quad = lane >> 4;
  const int wm = wv >> 1, wn = wv & 1;
  const int bm = blockIdx.y * 128;
  const int bn = blockIdx.x * 128;

  f32x4 acc[4][4];
#pragma unroll
  for (int i = 0; i < 4; ++i)
#pragma unroll
    for (int j = 0; j < 4; ++j) acc[i][j] = (f32x4){0.f, 0.f, 0.f, 0.f};

  const int srow = tid >> 2;
  const int kseg = (tid & 3) * 8;
  const unsigned short* Ag = A + (size_t)(bm + srow) * K + kseg;
  const unsigned short* Bg = B + (size_t)(bn + srow) * K + kseg;
  unsigned short* AsW = &As[wv * 512];
  unsigned short* BsW = &Bs[wv * 512];

  for (int k0 = 0; k0 < K; k0 += 32) {
    __syncthreads();
    async_copy16(Ag + k0, AsW);
    async_copy16(Ag + (size_t)64 * K + k0, AsW + 2048);
    async_copy16(Bg + k0, BsW);
    async_copy16(Bg + (size_t)64 * K + k0, BsW + 2048);
    __syncthreads();

    bf16x8 af[4], bf[4];
#pragma unroll
    for (int mt = 0; mt < 4; ++mt)
      af[mt] = *(const bf16x8*)&As[(wm * 64 + mt * 16 + l15) * 32 + quad * 8];
#pragma unroll
    for (int nt = 0; nt < 4; ++nt)
      bf[nt] = *(const bf16x8*)&Bs[(wn * 64 + nt * 16 + l15) * 32 + quad * 8];
#pragma unroll
    for (int mt = 0; mt < 4; ++mt)
#pragma unroll
      for (int nt = 0; nt < 4; ++nt)
        acc[mt][nt] = __builtin_amdgcn_mfma_f32_16x16x32_bf16(af[mt], bf[nt], acc[mt][nt], 0, 0, 0);
  }

  const bool isf32 = (*flagp != 0);
#pragma unroll
  for (int mt = 0; mt < 4; ++mt)
#pragma unroll
    for (int rr = 0; rr < 4; ++rr) {
      const int r = bm + wm * 64 + mt * 16 + quad * 4 + rr;
#pragma unroll
      for (int nt = 0; nt < 4; ++nt) {
        const int c = bn + wn * 64 + nt * 16 + l15;
        const float bias_c = isf32 ? ((const float*)biasv)[c]
                                   : bf2f(((const unsigned short*)biasv)[c]);
        const float o = acc[mt][nt][rr] + bias_c;
        if (isf32) ((float*)Cv)[(size_t)r * N + c] = o;
        else       ((unsigned short*)Cv)[(size_t)r * N + c] = f2bf(o);
      }
    }
}

// ---------------------------------------------------------------------------
extern "C" void kernel_launch(void* const* d_in, const int* in_sizes, int n_in,
                              void* d_out, int out_size, void* d_ws, size_t ws_size,
                              hipStream_t stream) {
  const void* x      = d_in[0];
  const void* w_qkv  = d_in[1];
  const void* w_proj = d_in[2];
  const void* b_proj = d_in[3];
  const void* q_g    = d_in[4];
  const void* q_b    = d_in[5];
  const void* k_g    = d_in[6];
  const void* k_b    = d_in[7];

  const size_t PLANE = (size_t)BATCH * NH * SEQ * HD;  // 4 Mi elems
  const int NX = BATCH * SEQ * DIM;
  const int NWQ = 3 * DIM * DIM;
  const int NWP = DIM * DIM;

  unsigned short* Qb  = (unsigned short*)d_ws;   // 8 MB
  unsigned short* Kb  = Qb + PLANE;              // 8 MB
  unsigned short* Vb  = Kb + PLANE;              // 8 MB
  unsigned short* VbT = Vb + PLANE;              // 8 MB
  unsigned short* xb  = VbT + PLANE;             // 8 MB (xb, later attnout)
  unsigned short* wqb = xb + PLANE;              // 6 MB
  unsigned short* wpb = wqb + NWQ;               // 2 MB
  int* flag = (int*)(wpb + NWP);                 // 4 B @ 48 MB

  hipLaunchKernelGGL(detect_dtype, dim3(1), dim3(256), 0, stream,
                     (const unsigned short*)w_qkv, flag);

  hipLaunchKernelGGL(convert_bf16, dim3(NX / 8 / 256), dim3(256), 0, stream,
                     x, xb, NX, flag);
  hipLaunchKernelGGL(convert_bf16, dim3(NWQ / 8 / 256), dim3(256), 0, stream,
                     w_qkv, wqb, NWQ, flag);
  hipLaunchKernelGGL(convert_bf16, dim3(NWP / 8 / 256), dim3(256), 0, stream,
                     w_proj, wpb, NWP, flag);

  // 1) QKV projection + fused LN/RoPE/scale -> bf16 Q/K/V planes
  {
    dim3 grid((3 * DIM) / 128, (BATCH * SEQ) / 128);
    hipLaunchKernelGGL(gemm_qkv, grid, dim3(256), 0, stream,
                       xb, wqb, Qb, Kb, Vb, q_g, q_b, k_g, k_b, flag);
  }
  // 2) V transpose -> VbT [BH][HD][S]
  {
    dim3 grid(SEQ / 64, BATCH * NH);
    hipLaunchKernelGGL(transpose_v, grid, dim3(256), 0, stream, Vb, VbT);
  }
  // 3) flash attention (transposed-space MFMA) -> bf16 attnout (xb slot)
  {
    dim3 grid(SEQ / 128, BATCH * NH);
    hipLaunchKernelGGL(attn_mfma2, grid, dim3(256), 0, stream,
                       Qb, Kb, VbT, xb);
  }
  // 4) output projection + bias -> d_out (flag dtype)
  {
    dim3 grid(DIM / 128, (BATCH * SEQ) / 128);
    hipLaunchKernelGGL(gemm_out, grid, dim3(256), 0, stream,
                       xb, wpb, b_proj, d_out, BATCH * SEQ, DIM, DIM, flag);
  }
}